// Round 8
// baseline (714.517 us; speedup 1.0000x reference)
//
#include <hip/hip_runtime.h>
#include <hip/hip_bf16.h>
#include <stdint.h>

// MambaConditioningBlock on gfx950.
// B=4, L=2048, D_MODEL=1024, D_INNER=2048, D_STATE=16, DT_RANK=64, D_CONV=4.
// R8 changes:
//  1) Scan exp-chain: S4D init has A[d][s] = -(s+1)*base[d], so
//     exp(d*A_s) = a1^(s+1): 1 exp + 15 muls (tree, depth 4) instead of 16 exp
//     (trans pipe is 1/4 VALU rate -> ~45% scan compute cut). Guarded by k_chk,
//     which verifies the structure on-device; general path kept for safety.
//  2) k_ada fused into k_wt4 -> k_pre (one fewer launch gap).

#define L_ 2048
#define DM 1024
#define DI 2048
#define DS 16
#define NC 32    // scan chunks
#define TC 64    // steps per chunk

typedef __bf16 bf16x8 __attribute__((ext_vector_type(8)));
typedef float f32x4 __attribute__((ext_vector_type(4)));

__device__ __forceinline__ float bf2f(unsigned int u) {
  union { unsigned int i; float f; } c;
  c.i = (u & 0xFFFFu) << 16;
  return c.f;
}
__device__ __forceinline__ unsigned short f2bf(float f) {
  union { float f; unsigned int i; } c; c.f = f;
  unsigned int x = c.i;
  return (unsigned short)((x + 0x7FFFu + ((x >> 16) & 1u)) >> 16);  // RNE
}
__device__ __forceinline__ float silu_f(float v) { return v / (1.f + __expf(-v)); }

// a1^(s+1) for s=0..15, multiply tree of depth 4
__device__ __forceinline__ void pow_chain(float a1, float* p) {
  p[0] = a1;
#pragma unroll
  for (int s = 1; s < 16; s++) p[s] = p[(s - 1) >> 1] * p[s >> 1];
}

// ---- async global->LDS, 16B per lane ----
__device__ __forceinline__ void async_cp16(unsigned short* lds, const unsigned short* g) {
  __builtin_amdgcn_global_load_lds(
      (const __attribute__((address_space(1))) unsigned int*)g,
      (__attribute__((address_space(3))) unsigned int*)lds, 16, 0, 0);
}

// =================== structure check: A[d][s] == (s+1)*A[d][0] ? ===================
__global__ __launch_bounds__(256) void k_chk(const float* __restrict__ A_log,
                                             int* __restrict__ flag) {
  __shared__ int ok;
  if (threadIdx.x == 0) ok = 1;
  __syncthreads();
  int good = 1;
  for (int i = threadIdx.x; i < DI * DS; i += 256) {
    const int s = i & 15, d = i >> 4;
    const float a = __expf(A_log[i]);
    const float expect = __expf(A_log[d * 16]) * (float)(s + 1);
    if (fabsf(a - expect) > 1e-4f * expect) good = 0;
  }
  if (!good) atomicAnd(&ok, 0);
  __syncthreads();
  if (threadIdx.x == 0) flag[0] = ok;
}

// =================== fused pre-pass: 4x weight transpose + ada GEMM ===================
// blocks [0,6528): src[K][N] fp32 -> dst[NP][K] bf16. blocks [6528,6576): mod.
__global__ __launch_bounds__(256) void k_pre(const float* __restrict__ s0, unsigned short* __restrict__ d0,
                                             const float* __restrict__ s1, unsigned short* __restrict__ d1,
                                             const float* __restrict__ s2, unsigned short* __restrict__ d2,
                                             const float* __restrict__ s3, unsigned short* __restrict__ d3,
                                             const float* __restrict__ cvec,
                                             const float* __restrict__ W_ada,
                                             const float* __restrict__ b_ada,
                                             float* __restrict__ mod) {
  __shared__ float tile[32][33];   // also reused as sc[1024] by the ada branch
  int bid = blockIdx.x;
  const int tid = threadIdx.x;
  if (bid >= 6528) {  // ada job: mod = silu(c) @ W_ada + b_ada
    bid -= 6528;
    const int b = bid / 12, jb = bid % 12;
    float* sc = &tile[0][0];
    for (int k = tid; k < DM; k += 256) sc[k] = silu_f(cvec[b * DM + k]);
    __syncthreads();
    const int j = jb * 256 + tid;
    float acc = b_ada[j];
#pragma unroll 8
    for (int k = 0; k < DM; k++) acc += sc[k] * W_ada[(size_t)k * 3072 + j];
    mod[b * 3072 + j] = acc;
    return;
  }
  const float* src; unsigned short* dst; int K, N, NP, kb, nb;
  if (bid < 4096)                { src = s0; dst = d0; K = 1024; N = 4096; NP = 4096; kb = bid & 31; nb = bid >> 5; }
  else if ((bid -= 4096) < 2048) { src = s1; dst = d1; K = 2048; N = 1024; NP = 1024; kb = bid & 63; nb = bid >> 6; }
  else if ((bid -= 2048) < 256)  { src = s2; dst = d2; K = 2048; N = 96;   NP = 128;  kb = bid & 63; nb = bid >> 6; }
  else { bid -= 256;               src = s3; dst = d3; K = 64;   N = 2048; NP = 2048; kb = bid & 1;  nb = bid >> 1; }
  const int kb0 = kb * 32, nb0 = nb * 32;
  const int tx = tid & 31, ty = tid >> 5;
#pragma unroll
  for (int i = 0; i < 4; i++) {
    int k = kb0 + ty + 8 * i, n = nb0 + tx;
    float v = 0.f;
    if (k < K && n < N) v = src[(size_t)k * N + n];
    tile[ty + 8 * i][tx] = v;
  }
  __syncthreads();
#pragma unroll
  for (int i = 0; i < 4; i++) {
    int n = nb0 + ty + 8 * i, k = kb0 + tx;
    if (n < NP && k < K) dst[(size_t)n * K + k] = f2bf(tile[tx][ty + 8 * i]);
  }
}

// =================== LayerNorm + adaLN modulation -> bf16 ===================
__global__ __launch_bounds__(256) void k_ln(const float* __restrict__ x,
                                            const float* __restrict__ mod,
                                            unsigned short* __restrict__ h) {
  const int row = blockIdx.x, b = row >> 11, tid = threadIdx.x;
  const float4 v = ((const float4*)(x + (size_t)row * DM))[tid];
  float s = v.x + v.y + v.z + v.w;
  float ss = v.x * v.x + v.y * v.y + v.z * v.z + v.w * v.w;
#pragma unroll
  for (int off = 32; off; off >>= 1) { s += __shfl_down(s, off); ss += __shfl_down(ss, off); }
  __shared__ float red[10];
  const int wv = tid >> 6, ln = tid & 63;
  if (ln == 0) { red[wv] = s; red[4 + wv] = ss; }
  __syncthreads();
  if (tid == 0) {
    float st = red[0] + red[1] + red[2] + red[3];
    float sst = red[4] + red[5] + red[6] + red[7];
    float mu = st * (1.f / DM);
    red[8] = mu;
    red[9] = rsqrtf(sst * (1.f / DM) - mu * mu + 1e-6f);
  }
  __syncthreads();
  const float mu = red[8], rstd = red[9];
  const int ccol = tid * 4;
  const float4 sc = *(const float4*)(mod + b * 3072 + ccol);
  const float4 sh = *(const float4*)(mod + b * 3072 + DM + ccol);
  uint2 p;
  p.x = (unsigned)f2bf((v.x - mu) * rstd * (1.f + sc.x) + sh.x) |
        ((unsigned)f2bf((v.y - mu) * rstd * (1.f + sc.y) + sh.y) << 16);
  p.y = (unsigned)f2bf((v.z - mu) * rstd * (1.f + sc.z) + sh.z) |
        ((unsigned)f2bf((v.w - mu) * rstd * (1.f + sc.w) + sh.w) << 16);
  *(uint2*)(h + (size_t)row * DM + ccol) = p;
}

// =================== bf16 MFMA GEMM, 128x128 tile, m97 structure ===================
struct GArgs {
  const unsigned short* A;
  const unsigned short* Bt;
  int lda, ldb, klen;
  float* f0;
  unsigned short* h0;
  unsigned short* h1;
  const float* c0;
  const float* c1;
};

template<int EPI>
__global__ __launch_bounds__(256, 2) void k_gemm(GArgs g) {
  __shared__ unsigned short sA[128 * 32];
  __shared__ unsigned short sB[128 * 32];
  const int tid = threadIdx.x;
  const int w = tid >> 6, lane = tid & 63;
  const int m0 = blockIdx.x * 128, n0 = blockIdx.y * 128;
  const int kstart = blockIdx.z * g.klen;
  const int r4 = lane >> 2;
  const int c8 = (lane & 3) * 8;
  const int rowA0 = w * 16 + r4, rowA1 = (w + 4) * 16 + r4;
  const unsigned short* gA0 = g.A + (size_t)(m0 + rowA0) * g.lda + kstart + c8;
  const unsigned short* gA1 = g.A + (size_t)(m0 + rowA1) * g.lda + kstart + c8;
  const unsigned short* gB0 = g.Bt + (size_t)(n0 + rowA0) * g.ldb + kstart + c8;
  const unsigned short* gB1 = g.Bt + (size_t)(n0 + rowA1) * g.ldb + kstart + c8;
  unsigned short* lA0 = sA + w * 512;
  unsigned short* lA1 = sA + (w + 4) * 512;
  unsigned short* lB0 = sB + w * 512;
  unsigned short* lB1 = sB + (w + 4) * 512;
  const int mw = (w & 1) * 64, nw = (w >> 1) * 64;
  const int row16 = lane & 15, k8 = (lane >> 4) * 8;
  f32x4 acc[4][4] = {};
  for (int kk = 0; kk < g.klen; kk += 32) {
    async_cp16(lA0, gA0); async_cp16(lA1, gA1);
    async_cp16(lB0, gB0); async_cp16(lB1, gB1);
    gA0 += 32; gA1 += 32; gB0 += 32; gB1 += 32;
    __syncthreads();
    bf16x8 av[4], bv[4];
#pragma unroll
    for (int i = 0; i < 4; i++)
      av[i] = *(const bf16x8*)(sA + (mw + 16 * i + row16) * 32 + k8);
#pragma unroll
    for (int j = 0; j < 4; j++)
      bv[j] = *(const bf16x8*)(sB + (nw + 16 * j + row16) * 32 + k8);
#pragma unroll
    for (int i = 0; i < 4; i++)
#pragma unroll
      for (int j = 0; j < 4; j++)
        acc[i][j] = __builtin_amdgcn_mfma_f32_16x16x32_bf16(av[i], bv[j], acc[i][j], 0, 0, 0);
    __syncthreads();
  }
  const int qr = (lane >> 4) * 4, cn = lane & 15;
#pragma unroll
  for (int i = 0; i < 4; i++) {
    const int m = m0 + mw + 16 * i + qr;
    const int b = m >> 11;
#pragma unroll
    for (int j = 0; j < 4; j++) {
      const int n = n0 + nw + 16 * j + cn;
      f32x4 v = acc[i][j];
      if constexpr (EPI == 0) {
        // in-proj: natural [m][d] stores; split xm / z
#pragma unroll
        for (int r = 0; r < 4; r++) {
          unsigned short* dst = (n < DI)
              ? g.h0 + (size_t)(m + r) * DI + n
              : g.h1 + (size_t)(m + r) * DI + (n - DI);
          *dst = f2bf(v[r]);
        }
      } else if constexpr (EPI == 1) {
        // x-proj split-K partial, transposed [z][n][m] fp32
        *(f32x4*)(g.f0 + ((size_t)(blockIdx.z * 128 + n)) * 8192 + m) = v;
      } else if constexpr (EPI == 2) {
        // dt-proj: +b_dt, softplus, bf16 [m][d]
        const float bn = g.c0[n];
#pragma unroll
        for (int r = 0; r < 4; r++) {
          float xx = v[r] + bn;
          g.h0[(size_t)(m + r) * DI + n] = f2bf((xx > 15.f) ? xx : __logf(1.f + __expf(xx)));
        }
      } else {
        // out-proj: out = x + gate * acc
        const float gate = g.c1[b * 3072 + 2048 + n];
#pragma unroll
        for (int r = 0; r < 4; r++) {
          size_t idx = (size_t)(m + r) * DM + n;
          g.f0[idx] = g.c0[idx] + gate * v[r];
        }
      }
    }
  }
}

// =================== causal depthwise conv (k=4) + silu, [m][d] -> [m][d] ===================
__global__ __launch_bounds__(256) void k_conv(const unsigned short* __restrict__ xm,
                                              const float* __restrict__ conv_w,
                                              const float* __restrict__ conv_b,
                                              unsigned short* __restrict__ u) {
  const int b = blockIdx.z;
  const int t = blockIdx.x * 32 + (threadIdx.x >> 3);
  const int d = blockIdx.y * 64 + (threadIdx.x & 7) * 8;
  const size_t rowbase = ((size_t)(b * L_ + t)) * DI + d;
  uint4 r3 = *(const uint4*)(xm + rowbase);
  uint4 r0 = make_uint4(0, 0, 0, 0), r1 = r0, r2 = r0;
  if (t >= 3) r0 = *(const uint4*)(xm + rowbase - 3 * DI);
  if (t >= 2) r1 = *(const uint4*)(xm + rowbase - 2 * DI);
  if (t >= 1) r2 = *(const uint4*)(xm + rowbase - 1 * DI);
  float x0[8], x1[8], x2[8], x3[8];
  const unsigned* p0 = (const unsigned*)&r0;
  const unsigned* p1 = (const unsigned*)&r1;
  const unsigned* p2 = (const unsigned*)&r2;
  const unsigned* p3 = (const unsigned*)&r3;
#pragma unroll
  for (int q = 0; q < 4; q++) {
    x0[2 * q] = bf2f(p0[q]); x0[2 * q + 1] = bf2f(p0[q] >> 16);
    x1[2 * q] = bf2f(p1[q]); x1[2 * q + 1] = bf2f(p1[q] >> 16);
    x2[2 * q] = bf2f(p2[q]); x2[2 * q + 1] = bf2f(p2[q] >> 16);
    x3[2 * q] = bf2f(p3[q]); x3[2 * q + 1] = bf2f(p3[q] >> 16);
  }
  const f32x4 cb0 = *(const f32x4*)(conv_b + d);
  const f32x4 cb1 = *(const f32x4*)(conv_b + d + 4);
  unsigned out[4];
#pragma unroll
  for (int j = 0; j < 8; j++) {
    const f32x4 wj = *(const f32x4*)(conv_w + (size_t)(d + j) * 4);
    const float cb = (j < 4) ? cb0[j] : cb1[j - 4];
    float a = cb + wj[0] * x0[j] + wj[1] * x1[j] + wj[2] * x2[j] + wj[3] * x3[j];
    unsigned short us = f2bf(silu_f(a));
    if (j & 1) out[j >> 1] |= ((unsigned)us << 16);
    else out[j >> 1] = us;
  }
  *(uint4*)(u + rowbase) = make_uint4(out[0], out[1], out[2], out[3]);
}

// =================== reduce split-K partials, split dt / pack BC[m][32] ===================
__global__ __launch_bounds__(256) void k_xsplit(const float* __restrict__ pt,
                                                unsigned short* __restrict__ dtb,
                                                float* __restrict__ BC) {
  const int bx = blockIdx.x;
  const int n = bx >> 5;
  const int m = ((bx & 31) << 8) + threadIdx.x;
  float v = pt[(size_t)n * 8192 + m] + pt[(size_t)(128 + n) * 8192 + m] +
            pt[(size_t)(256 + n) * 8192 + m] + pt[(size_t)(384 + n) * 8192 + m];
  if (n < 64) dtb[(size_t)m * 64 + n] = f2bf(v);
  else if (n < 80) BC[(size_t)m * 32 + (n - 64)] = v;
  else BC[(size_t)m * 32 + 16 + (n - 80)] = v;
}

// =================== scan phase A: local chunk scan, emit h_loc[16] + sum(delta) ===================
__global__ __launch_bounds__(256, 4) void k_scanA(const unsigned short* __restrict__ delta,
                                                  const unsigned short* __restrict__ u,
                                                  const float* __restrict__ BC,
                                                  const float* __restrict__ A_log,
                                                  const int* __restrict__ flag,
                                                  float* __restrict__ hloc,
                                                  float* __restrict__ dsum) {
  const int b = blockIdx.y, c = blockIdx.z;
  const int d = blockIdx.x * 256 + threadIdx.x;
  const int fast = flag[0];
  const size_t mbase = (size_t)(b * L_ + c * TC);
  const unsigned short* dp = delta + mbase * DI + d;
  const unsigned short* up = u + mbase * DI + d;
  const float* bc = BC + mbase * 32;
  float h[16];
#pragma unroll
  for (int s = 0; s < 16; s++) h[s] = 0.f;
  float sd = 0.f;
  if (fast) {
    const float As0 = -__expf(A_log[(size_t)d * 16]);
    for (int t8 = 0; t8 < TC; t8 += 8) {
      float dv[8], uvf[8];
#pragma unroll
      for (int i = 0; i < 8; i++) dv[i] = bf2f(dp[(size_t)(t8 + i) * DI]);
#pragma unroll
      for (int i = 0; i < 8; i++) uvf[i] = bf2f(up[(size_t)(t8 + i) * DI]);
#pragma unroll
      for (int i = 0; i < 8; i++) {
        const float dvi = dv[i];
        const float w = dvi * uvf[i];
        sd += dvi;
        const float* bct = bc + (size_t)(t8 + i) * 32;
        float p[16];
        pow_chain(__expf(dvi * As0), p);
#pragma unroll
        for (int q = 0; q < 4; q++) {
          const f32x4 bq = *(const f32x4*)(bct + q * 4);
#pragma unroll
          for (int j = 0; j < 4; j++) {
            const int s = q * 4 + j;
            h[s] = p[s] * h[s] + w * bq[j];
          }
        }
      }
    }
  } else {
    float As[16];
#pragma unroll
    for (int q = 0; q < 4; q++) {
      const f32x4 av = *(const f32x4*)(A_log + (size_t)d * 16 + q * 4);
#pragma unroll
      for (int j = 0; j < 4; j++) As[q * 4 + j] = -__expf(av[j]);
    }
    for (int t8 = 0; t8 < TC; t8 += 8) {
      float dv[8], uvf[8];
#pragma unroll
      for (int i = 0; i < 8; i++) dv[i] = bf2f(dp[(size_t)(t8 + i) * DI]);
#pragma unroll
      for (int i = 0; i < 8; i++) uvf[i] = bf2f(up[(size_t)(t8 + i) * DI]);
#pragma unroll
      for (int i = 0; i < 8; i++) {
        const float dvi = dv[i];
        const float w = dvi * uvf[i];
        sd += dvi;
        const float* bct = bc + (size_t)(t8 + i) * 32;
#pragma unroll
        for (int q = 0; q < 4; q++) {
          const f32x4 bq = *(const f32x4*)(bct + q * 4);
#pragma unroll
          for (int j = 0; j < 4; j++) {
            const int s = q * 4 + j;
            h[s] = __expf(dvi * As[s]) * h[s] + w * bq[j];
          }
        }
      }
    }
  }
  float* hl = hloc + (((size_t)(b * NC + c)) * DI + d) * 16;
#pragma unroll
  for (int q = 0; q < 4; q++) {
    f32x4 v = {h[q * 4], h[q * 4 + 1], h[q * 4 + 2], h[q * 4 + 3]};
    *(f32x4*)(hl + q * 4) = v;
  }
  dsum[((size_t)(b * NC + c)) * DI + d] = sd;
}

// =================== scan phase B: chunk prefix per (b,d) ===================
__global__ __launch_bounds__(256) void k_scanB(const float* __restrict__ hloc,
                                               const float* __restrict__ dsum,
                                               const float* __restrict__ A_log,
                                               const int* __restrict__ flag,
                                               float* __restrict__ hin) {
  const int i = blockIdx.x * 256 + threadIdx.x;   // 8192 = B*DI
  const int b = i >> 11, d = i & 2047;
  const int fast = flag[0];
  float As[16];
  const float As0 = -__expf(A_log[(size_t)d * 16]);
  if (!fast) {
#pragma unroll
    for (int q = 0; q < 4; q++) {
      const f32x4 av = *(const f32x4*)(A_log + (size_t)d * 16 + q * 4);
#pragma unroll
      for (int j = 0; j < 4; j++) As[q * 4 + j] = -__expf(av[j]);
    }
  }
  float H[16];
#pragma unroll
  for (int s = 0; s < 16; s++) H[s] = 0.f;
  for (int c = 0; c < NC; c++) {
    float* hp = hin + (((size_t)(b * NC + c)) * DI + d) * 16;
#pragma unroll
    for (int q = 0; q < 4; q++) {
      f32x4 v = {H[q * 4], H[q * 4 + 1], H[q * 4 + 2], H[q * 4 + 3]};
      *(f32x4*)(hp + q * 4) = v;
    }
    if (c < NC - 1) {
      const float sd = dsum[((size_t)(b * NC + c)) * DI + d];
      const float* hl = hloc + (((size_t)(b * NC + c)) * DI + d) * 16;
      if (fast) {
        float p[16];
        pow_chain(__expf(sd * As0), p);
#pragma unroll
        for (int s = 0; s < 16; s++) H[s] = p[s] * H[s] + hl[s];
      } else {
#pragma unroll
        for (int s = 0; s < 16; s++) H[s] = __expf(sd * As[s]) * H[s] + hl[s];
      }
    }
  }
}

// =================== scan phase C: apply carry, y = C.h, fused skip + silu(z) gate ===================
__global__ __launch_bounds__(256, 4) void k_scanC(const unsigned short* __restrict__ delta,
                                                  const unsigned short* __restrict__ u,
                                                  const unsigned short* __restrict__ z,
                                                  const float* __restrict__ BC,
                                                  const float* __restrict__ A_log,
                                                  const float* __restrict__ Dsk,
                                                  const int* __restrict__ flag,
                                                  const float* __restrict__ hin,
                                                  unsigned short* __restrict__ y) {
  const int b = blockIdx.y, c = blockIdx.z;
  const int d = blockIdx.x * 256 + threadIdx.x;
  const int fast = flag[0];
  const size_t mbase = (size_t)(b * L_ + c * TC);
  const unsigned short* dp = delta + mbase * DI + d;
  const unsigned short* up = u + mbase * DI + d;
  const unsigned short* zp = z + mbase * DI + d;
  const float* bc = BC + mbase * 32;
  const float dsk = Dsk[d];
  float h[16];
  const float* hp = hin + (((size_t)(b * NC + c)) * DI + d) * 16;
#pragma unroll
  for (int q = 0; q < 4; q++) {
    const f32x4 v = *(const f32x4*)(hp + q * 4);
#pragma unroll
    for (int j = 0; j < 4; j++) h[q * 4 + j] = v[j];
  }
  unsigned short* yp = y + mbase * DI + d;
  if (fast) {
    const float As0 = -__expf(A_log[(size_t)d * 16]);
    for (int t8 = 0; t8 < TC; t8 += 8) {
      float dv[8], uvf[8], zvf[8];
#pragma unroll
      for (int i = 0; i < 8; i++) dv[i] = bf2f(dp[(size_t)(t8 + i) * DI]);
#pragma unroll
      for (int i = 0; i < 8; i++) uvf[i] = bf2f(up[(size_t)(t8 + i) * DI]);
#pragma unroll
      for (int i = 0; i < 8; i++) zvf[i] = bf2f(zp[(size_t)(t8 + i) * DI]);
#pragma unroll
      for (int i = 0; i < 8; i++) {
        const float dvi = dv[i];
        const float w = dvi * uvf[i];
        const float* bct = bc + (size_t)(t8 + i) * 32;
        float p[16];
        pow_chain(__expf(dvi * As0), p);
        float y0 = 0.f, y1 = 0.f;
#pragma unroll
        for (int q = 0; q < 4; q++) {
          const f32x4 bq = *(const f32x4*)(bct + q * 4);
          const f32x4 cq = *(const f32x4*)(bct + 16 + q * 4);
#pragma unroll
          for (int j = 0; j < 4; j++) {
            const int s = q * 4 + j;
            h[s] = p[s] * h[s] + w * bq[j];
            if (j & 1) y1 += h[s] * cq[j]; else y0 += h[s] * cq[j];
          }
        }
        const float yt = (y0 + y1 + uvf[i] * dsk) * silu_f(zvf[i]);
        yp[(size_t)(t8 + i) * DI] = f2bf(yt);
      }
    }
  } else {
    float As[16];
#pragma unroll
    for (int q = 0; q < 4; q++) {
      const f32x4 av = *(const f32x4*)(A_log + (size_t)d * 16 + q * 4);
#pragma unroll
      for (int j = 0; j < 4; j++) As[q * 4 + j] = -__expf(av[j]);
    }
    for (int t8 = 0; t8 < TC; t8 += 8) {
      float dv[8], uvf[8], zvf[8];
#pragma unroll
      for (int i = 0; i < 8; i++) dv[i] = bf2f(dp[(size_t)(t8 + i) * DI]);
#pragma unroll
      for (int i = 0; i < 8; i++) uvf[i] = bf2f(up[(size_t)(t8 + i) * DI]);
#pragma unroll
      for (int i = 0; i < 8; i++) zvf[i] = bf2f(zp[(size_t)(t8 + i) * DI]);
#pragma unroll
      for (int i = 0; i < 8; i++) {
        const float dvi = dv[i];
        const float w = dvi * uvf[i];
        const float* bct = bc + (size_t)(t8 + i) * 32;
        float y0 = 0.f, y1 = 0.f;
#pragma unroll
        for (int q = 0; q < 4; q++) {
          const f32x4 bq = *(const f32x4*)(bct + q * 4);
          const f32x4 cq = *(const f32x4*)(bct + 16 + q * 4);
#pragma unroll
          for (int j = 0; j < 4; j++) {
            const int s = q * 4 + j;
            h[s] = __expf(dvi * As[s]) * h[s] + w * bq[j];
            if (j & 1) y1 += h[s] * cq[j]; else y0 += h[s] * cq[j];
          }
        }
        const float yt = (y0 + y1 + uvf[i] * dsk) * silu_f(zvf[i]);
        yp[(size_t)(t8 + i) * DI] = f2bf(yt);
      }
    }
  }
}

// =================== launch ===================
extern "C" void kernel_launch(void* const* d_in, const int* in_sizes, int n_in,
                              void* d_out, int out_size, void* d_ws, size_t ws_size,
                              hipStream_t stream) {
  const float* x      = (const float*)d_in[0];
  const float* c      = (const float*)d_in[1];
  const float* W_in   = (const float*)d_in[2];
  const float* conv_w = (const float*)d_in[3];
  const float* conv_b = (const float*)d_in[4];
  const float* W_xp   = (const float*)d_in[5];
  const float* W_dt   = (const float*)d_in[6];
  const float* b_dt   = (const float*)d_in[7];
  const float* A_log  = (const float*)d_in[8];
  const float* D_skip = (const float*)d_in[9];
  const float* W_out  = (const float*)d_in[10];
  const float* W_ada  = (const float*)d_in[11];
  const float* b_ada  = (const float*)d_in[12];
  float* out = (float*)d_out;

  char* ws = (char*)d_ws;
  size_t off = 0;
  auto take = [&](size_t bytes) {
    char* p = ws + off;
    off += (bytes + 255) & ~(size_t)255;
    return p;
  };
  // Footprint: R7 + 256B flag (R7 had >=32MB slack vs the R5 layout that fit).
  float* mod             = (float*)take((size_t)4 * 3072 * 4);
  unsigned short* Wt_in  = (unsigned short*)take((size_t)4096 * 1024 * 2);
  unsigned short* Wt_out = (unsigned short*)take((size_t)1024 * 2048 * 2);
  unsigned short* Wt_xp  = (unsigned short*)take((size_t)128 * 2048 * 2);
  unsigned short* Wt_dt  = (unsigned short*)take((size_t)2048 * 64 * 2);
  unsigned short* h_bf   = (unsigned short*)take((size_t)8192 * 1024 * 2);      // 16MB; then part_T, then hin
  unsigned short* xm     = (unsigned short*)take((size_t)4 * 2048 * 2048 * 2);  // 32MB [m][d]; then y_bf
  unsigned short* z_bf   = (unsigned short*)take((size_t)4 * 2048 * 2048 * 2);  // 32MB [m][d]
  unsigned short* scanws = (unsigned short*)take((size_t)4 * 2048 * 2048 * 2);  // 32MB; hloc(16MB)+dsum(1MB)
  unsigned short* u_bf   = (unsigned short*)take((size_t)8192 * 2048 * 2);      // 32MB [m][d]; u==xc
  unsigned short* delta  = (unsigned short*)take((size_t)8192 * 2048 * 2);      // 32MB [m][d] bf16
  unsigned short* dt_bf  = (unsigned short*)take((size_t)8192 * 64 * 2);
  float* BC              = (float*)take((size_t)4 * 2048 * 32 * 4);             // [m][32]: B|C packed
  int* flag              = (int*)take(256);
  float* part_T = (float*)h_bf;                                   // dead after k_xsplit
  float* hin    = (float*)h_bf;                                   // 16MB exact; written by scanB
  float* hloc   = (float*)scanws;                                 // 16MB
  float* dsum   = (float*)(scanws + (size_t)8 * 1024 * 1024);     // +16MB, 1MB
  unsigned short* y_bf = xm;                                      // xm dead after conv

  // 0. A-structure check (enables scan exp-chain fast path)
  k_chk<<<1, 256, 0, stream>>>(A_log, flag);
  // 1. fused pre-pass: weight transpose x4 + ada GEMM (6528 + 48 blocks)
  k_pre<<<6576, 256, 0, stream>>>(W_in, Wt_in, W_out, Wt_out, W_xp, Wt_xp, W_dt, Wt_dt,
                                  c, W_ada, b_ada, mod);
  // 2. LN + modulation
  k_ln<<<8192, 256, 0, stream>>>(x, mod, h_bf);
  // 3. in-proj -> xm[m][d], z[m][d]
  GArgs a1{h_bf, Wt_in, 1024, 1024, 1024, nullptr, xm, z_bf, nullptr, nullptr};
  k_gemm<0><<<dim3(64, 32), 256, 0, stream>>>(a1);
  // 4. conv + silu -> u[m][d]
  k_conv<<<dim3(64, 32, 4), 256, 0, stream>>>(xm, conv_w, conv_b, u_bf);
  // 5. x-proj (split-K)
  GArgs a2{u_bf, Wt_xp, 2048, 2048, 512, part_T, nullptr, nullptr, nullptr, nullptr};
  k_gemm<1><<<dim3(64, 1, 4), 256, 0, stream>>>(a2);
  // 6. reduce + split (dt rows; BC[m][32])
  k_xsplit<<<3072, 256, 0, stream>>>(part_T, dt_bf, BC);
  // 7. dt-proj + softplus -> delta[m][d] bf16
  GArgs a3{dt_bf, Wt_dt, 64, 64, 64, nullptr, delta, nullptr, b_dt, nullptr};
  k_gemm<2><<<dim3(64, 16), 256, 0, stream>>>(a3);
  // 8. chunked selective scan, [m][d] coalesced, exp-chain fast path
  k_scanA<<<dim3(8, 4, NC - 1), 256, 0, stream>>>(delta, u_bf, BC, A_log, flag, hloc, dsum);
  k_scanB<<<32, 256, 0, stream>>>(hloc, dsum, A_log, flag, hin);
  k_scanC<<<dim3(8, 4, NC), 256, 0, stream>>>(delta, u_bf, z_bf, BC, A_log, D_skip, flag, hin, y_bf);
  // 9. out-proj + residual + gate
  GArgs a4{y_bf, Wt_out, 2048, 2048, 2048, out, nullptr, nullptr, x, mod};
  k_gemm<3><<<dim3(64, 8), 256, 0, stream>>>(a4);
}

// Round 9
// 612.204 us; speedup vs baseline: 1.1671x; 1.1671x over previous
//
#include <hip/hip_runtime.h>
#include <hip/hip_bf16.h>
#include <stdint.h>

// MambaConditioningBlock on gfx950.
// B=4, L=2048, D_MODEL=1024, D_INNER=2048, D_STATE=16, DT_RANK=64, D_CONV=4.
// R9: R8's pow_chain p[16] array blew the 64-VGPR cap (launch_bounds 256,4)
// -> scratch spill (scanC WRITE_SIZE 230MB vs 16MB ideal, 152us). Same
// exp->mul algebra, but powers computed INCREMENTALLY (pp *= a1 consumed in
// ascending s order): +1 register instead of +16. Fast path also drops As[16]
// entirely, so worst-case allocation ~= R7's (which fit spill-free).

#define L_ 2048
#define DM 1024
#define DI 2048
#define DS 16
#define NC 32    // scan chunks
#define TC 64    // steps per chunk

typedef __bf16 bf16x8 __attribute__((ext_vector_type(8)));
typedef float f32x4 __attribute__((ext_vector_type(4)));

__device__ __forceinline__ float bf2f(unsigned int u) {
  union { unsigned int i; float f; } c;
  c.i = (u & 0xFFFFu) << 16;
  return c.f;
}
__device__ __forceinline__ unsigned short f2bf(float f) {
  union { float f; unsigned int i; } c; c.f = f;
  unsigned int x = c.i;
  return (unsigned short)((x + 0x7FFFu + ((x >> 16) & 1u)) >> 16);  // RNE
}
__device__ __forceinline__ float silu_f(float v) { return v / (1.f + __expf(-v)); }

// ---- async global->LDS, 16B per lane ----
__device__ __forceinline__ void async_cp16(unsigned short* lds, const unsigned short* g) {
  __builtin_amdgcn_global_load_lds(
      (const __attribute__((address_space(1))) unsigned int*)g,
      (__attribute__((address_space(3))) unsigned int*)lds, 16, 0, 0);
}

// =================== structure check: A[d][s] == (s+1)*A[d][0] ? ===================
__global__ __launch_bounds__(256) void k_chk(const float* __restrict__ A_log,
                                             int* __restrict__ flag) {
  __shared__ int ok;
  if (threadIdx.x == 0) ok = 1;
  __syncthreads();
  int good = 1;
  for (int i = threadIdx.x; i < DI * DS; i += 256) {
    const int s = i & 15, d = i >> 4;
    const float a = __expf(A_log[i]);
    const float expect = __expf(A_log[d * 16]) * (float)(s + 1);
    if (fabsf(a - expect) > 1e-4f * expect) good = 0;
  }
  if (!good) atomicAnd(&ok, 0);
  __syncthreads();
  if (threadIdx.x == 0) flag[0] = ok;
}

// =================== fused pre-pass: 4x weight transpose + ada GEMM ===================
// blocks [0,6528): src[K][N] fp32 -> dst[NP][K] bf16. blocks [6528,6576): mod.
__global__ __launch_bounds__(256) void k_pre(const float* __restrict__ s0, unsigned short* __restrict__ d0,
                                             const float* __restrict__ s1, unsigned short* __restrict__ d1,
                                             const float* __restrict__ s2, unsigned short* __restrict__ d2,
                                             const float* __restrict__ s3, unsigned short* __restrict__ d3,
                                             const float* __restrict__ cvec,
                                             const float* __restrict__ W_ada,
                                             const float* __restrict__ b_ada,
                                             float* __restrict__ mod) {
  __shared__ float tile[32][33];   // also reused as sc[1024] by the ada branch
  int bid = blockIdx.x;
  const int tid = threadIdx.x;
  if (bid >= 6528) {  // ada job: mod = silu(c) @ W_ada + b_ada
    bid -= 6528;
    const int b = bid / 12, jb = bid % 12;
    float* sc = &tile[0][0];
    for (int k = tid; k < DM; k += 256) sc[k] = silu_f(cvec[b * DM + k]);
    __syncthreads();
    const int j = jb * 256 + tid;
    float acc = b_ada[j];
#pragma unroll 8
    for (int k = 0; k < DM; k++) acc += sc[k] * W_ada[(size_t)k * 3072 + j];
    mod[b * 3072 + j] = acc;
    return;
  }
  const float* src; unsigned short* dst; int K, N, NP, kb, nb;
  if (bid < 4096)                { src = s0; dst = d0; K = 1024; N = 4096; NP = 4096; kb = bid & 31; nb = bid >> 5; }
  else if ((bid -= 4096) < 2048) { src = s1; dst = d1; K = 2048; N = 1024; NP = 1024; kb = bid & 63; nb = bid >> 6; }
  else if ((bid -= 2048) < 256)  { src = s2; dst = d2; K = 2048; N = 96;   NP = 128;  kb = bid & 63; nb = bid >> 6; }
  else { bid -= 256;               src = s3; dst = d3; K = 64;   N = 2048; NP = 2048; kb = bid & 1;  nb = bid >> 1; }
  const int kb0 = kb * 32, nb0 = nb * 32;
  const int tx = tid & 31, ty = tid >> 5;
#pragma unroll
  for (int i = 0; i < 4; i++) {
    int k = kb0 + ty + 8 * i, n = nb0 + tx;
    float v = 0.f;
    if (k < K && n < N) v = src[(size_t)k * N + n];
    tile[ty + 8 * i][tx] = v;
  }
  __syncthreads();
#pragma unroll
  for (int i = 0; i < 4; i++) {
    int n = nb0 + ty + 8 * i, k = kb0 + tx;
    if (n < NP && k < K) dst[(size_t)n * K + k] = f2bf(tile[tx][ty + 8 * i]);
  }
}

// =================== LayerNorm + adaLN modulation -> bf16 ===================
__global__ __launch_bounds__(256) void k_ln(const float* __restrict__ x,
                                            const float* __restrict__ mod,
                                            unsigned short* __restrict__ h) {
  const int row = blockIdx.x, b = row >> 11, tid = threadIdx.x;
  const float4 v = ((const float4*)(x + (size_t)row * DM))[tid];
  float s = v.x + v.y + v.z + v.w;
  float ss = v.x * v.x + v.y * v.y + v.z * v.z + v.w * v.w;
#pragma unroll
  for (int off = 32; off; off >>= 1) { s += __shfl_down(s, off); ss += __shfl_down(ss, off); }
  __shared__ float red[10];
  const int wv = tid >> 6, ln = tid & 63;
  if (ln == 0) { red[wv] = s; red[4 + wv] = ss; }
  __syncthreads();
  if (tid == 0) {
    float st = red[0] + red[1] + red[2] + red[3];
    float sst = red[4] + red[5] + red[6] + red[7];
    float mu = st * (1.f / DM);
    red[8] = mu;
    red[9] = rsqrtf(sst * (1.f / DM) - mu * mu + 1e-6f);
  }
  __syncthreads();
  const float mu = red[8], rstd = red[9];
  const int ccol = tid * 4;
  const float4 sc = *(const float4*)(mod + b * 3072 + ccol);
  const float4 sh = *(const float4*)(mod + b * 3072 + DM + ccol);
  uint2 p;
  p.x = (unsigned)f2bf((v.x - mu) * rstd * (1.f + sc.x) + sh.x) |
        ((unsigned)f2bf((v.y - mu) * rstd * (1.f + sc.y) + sh.y) << 16);
  p.y = (unsigned)f2bf((v.z - mu) * rstd * (1.f + sc.z) + sh.z) |
        ((unsigned)f2bf((v.w - mu) * rstd * (1.f + sc.w) + sh.w) << 16);
  *(uint2*)(h + (size_t)row * DM + ccol) = p;
}

// =================== bf16 MFMA GEMM, 128x128 tile, m97 structure ===================
struct GArgs {
  const unsigned short* A;
  const unsigned short* Bt;
  int lda, ldb, klen;
  float* f0;
  unsigned short* h0;
  unsigned short* h1;
  const float* c0;
  const float* c1;
};

template<int EPI>
__global__ __launch_bounds__(256, 2) void k_gemm(GArgs g) {
  __shared__ unsigned short sA[128 * 32];
  __shared__ unsigned short sB[128 * 32];
  const int tid = threadIdx.x;
  const int w = tid >> 6, lane = tid & 63;
  const int m0 = blockIdx.x * 128, n0 = blockIdx.y * 128;
  const int kstart = blockIdx.z * g.klen;
  const int r4 = lane >> 2;
  const int c8 = (lane & 3) * 8;
  const int rowA0 = w * 16 + r4, rowA1 = (w + 4) * 16 + r4;
  const unsigned short* gA0 = g.A + (size_t)(m0 + rowA0) * g.lda + kstart + c8;
  const unsigned short* gA1 = g.A + (size_t)(m0 + rowA1) * g.lda + kstart + c8;
  const unsigned short* gB0 = g.Bt + (size_t)(n0 + rowA0) * g.ldb + kstart + c8;
  const unsigned short* gB1 = g.Bt + (size_t)(n0 + rowA1) * g.ldb + kstart + c8;
  unsigned short* lA0 = sA + w * 512;
  unsigned short* lA1 = sA + (w + 4) * 512;
  unsigned short* lB0 = sB + w * 512;
  unsigned short* lB1 = sB + (w + 4) * 512;
  const int mw = (w & 1) * 64, nw = (w >> 1) * 64;
  const int row16 = lane & 15, k8 = (lane >> 4) * 8;
  f32x4 acc[4][4] = {};
  for (int kk = 0; kk < g.klen; kk += 32) {
    async_cp16(lA0, gA0); async_cp16(lA1, gA1);
    async_cp16(lB0, gB0); async_cp16(lB1, gB1);
    gA0 += 32; gA1 += 32; gB0 += 32; gB1 += 32;
    __syncthreads();
    bf16x8 av[4], bv[4];
#pragma unroll
    for (int i = 0; i < 4; i++)
      av[i] = *(const bf16x8*)(sA + (mw + 16 * i + row16) * 32 + k8);
#pragma unroll
    for (int j = 0; j < 4; j++)
      bv[j] = *(const bf16x8*)(sB + (nw + 16 * j + row16) * 32 + k8);
#pragma unroll
    for (int i = 0; i < 4; i++)
#pragma unroll
      for (int j = 0; j < 4; j++)
        acc[i][j] = __builtin_amdgcn_mfma_f32_16x16x32_bf16(av[i], bv[j], acc[i][j], 0, 0, 0);
    __syncthreads();
  }
  const int qr = (lane >> 4) * 4, cn = lane & 15;
#pragma unroll
  for (int i = 0; i < 4; i++) {
    const int m = m0 + mw + 16 * i + qr;
    const int b = m >> 11;
#pragma unroll
    for (int j = 0; j < 4; j++) {
      const int n = n0 + nw + 16 * j + cn;
      f32x4 v = acc[i][j];
      if constexpr (EPI == 0) {
        // in-proj: natural [m][d] stores; split xm / z
#pragma unroll
        for (int r = 0; r < 4; r++) {
          unsigned short* dst = (n < DI)
              ? g.h0 + (size_t)(m + r) * DI + n
              : g.h1 + (size_t)(m + r) * DI + (n - DI);
          *dst = f2bf(v[r]);
        }
      } else if constexpr (EPI == 1) {
        // x-proj split-K partial, transposed [z][n][m] fp32
        *(f32x4*)(g.f0 + ((size_t)(blockIdx.z * 128 + n)) * 8192 + m) = v;
      } else if constexpr (EPI == 2) {
        // dt-proj: +b_dt, softplus, bf16 [m][d]
        const float bn = g.c0[n];
#pragma unroll
        for (int r = 0; r < 4; r++) {
          float xx = v[r] + bn;
          g.h0[(size_t)(m + r) * DI + n] = f2bf((xx > 15.f) ? xx : __logf(1.f + __expf(xx)));
        }
      } else {
        // out-proj: out = x + gate * acc
        const float gate = g.c1[b * 3072 + 2048 + n];
#pragma unroll
        for (int r = 0; r < 4; r++) {
          size_t idx = (size_t)(m + r) * DM + n;
          g.f0[idx] = g.c0[idx] + gate * v[r];
        }
      }
    }
  }
}

// =================== causal depthwise conv (k=4) + silu, [m][d] -> [m][d] ===================
__global__ __launch_bounds__(256) void k_conv(const unsigned short* __restrict__ xm,
                                              const float* __restrict__ conv_w,
                                              const float* __restrict__ conv_b,
                                              unsigned short* __restrict__ u) {
  const int b = blockIdx.z;
  const int t = blockIdx.x * 32 + (threadIdx.x >> 3);
  const int d = blockIdx.y * 64 + (threadIdx.x & 7) * 8;
  const size_t rowbase = ((size_t)(b * L_ + t)) * DI + d;
  uint4 r3 = *(const uint4*)(xm + rowbase);
  uint4 r0 = make_uint4(0, 0, 0, 0), r1 = r0, r2 = r0;
  if (t >= 3) r0 = *(const uint4*)(xm + rowbase - 3 * DI);
  if (t >= 2) r1 = *(const uint4*)(xm + rowbase - 2 * DI);
  if (t >= 1) r2 = *(const uint4*)(xm + rowbase - 1 * DI);
  float x0[8], x1[8], x2[8], x3[8];
  const unsigned* p0 = (const unsigned*)&r0;
  const unsigned* p1 = (const unsigned*)&r1;
  const unsigned* p2 = (const unsigned*)&r2;
  const unsigned* p3 = (const unsigned*)&r3;
#pragma unroll
  for (int q = 0; q < 4; q++) {
    x0[2 * q] = bf2f(p0[q]); x0[2 * q + 1] = bf2f(p0[q] >> 16);
    x1[2 * q] = bf2f(p1[q]); x1[2 * q + 1] = bf2f(p1[q] >> 16);
    x2[2 * q] = bf2f(p2[q]); x2[2 * q + 1] = bf2f(p2[q] >> 16);
    x3[2 * q] = bf2f(p3[q]); x3[2 * q + 1] = bf2f(p3[q] >> 16);
  }
  const f32x4 cb0 = *(const f32x4*)(conv_b + d);
  const f32x4 cb1 = *(const f32x4*)(conv_b + d + 4);
  unsigned out[4];
#pragma unroll
  for (int j = 0; j < 8; j++) {
    const f32x4 wj = *(const f32x4*)(conv_w + (size_t)(d + j) * 4);
    const float cb = (j < 4) ? cb0[j] : cb1[j - 4];
    float a = cb + wj[0] * x0[j] + wj[1] * x1[j] + wj[2] * x2[j] + wj[3] * x3[j];
    unsigned short us = f2bf(silu_f(a));
    if (j & 1) out[j >> 1] |= ((unsigned)us << 16);
    else out[j >> 1] = us;
  }
  *(uint4*)(u + rowbase) = make_uint4(out[0], out[1], out[2], out[3]);
}

// =================== reduce split-K partials, split dt / pack BC[m][32] ===================
__global__ __launch_bounds__(256) void k_xsplit(const float* __restrict__ pt,
                                                unsigned short* __restrict__ dtb,
                                                float* __restrict__ BC) {
  const int bx = blockIdx.x;
  const int n = bx >> 5;
  const int m = ((bx & 31) << 8) + threadIdx.x;
  float v = pt[(size_t)n * 8192 + m] + pt[(size_t)(128 + n) * 8192 + m] +
            pt[(size_t)(256 + n) * 8192 + m] + pt[(size_t)(384 + n) * 8192 + m];
  if (n < 64) dtb[(size_t)m * 64 + n] = f2bf(v);
  else if (n < 80) BC[(size_t)m * 32 + (n - 64)] = v;
  else BC[(size_t)m * 32 + 16 + (n - 80)] = v;
}

// =================== scan phase A: local chunk scan, emit h_loc[16] + sum(delta) ===================
__global__ __launch_bounds__(256, 4) void k_scanA(const unsigned short* __restrict__ delta,
                                                  const unsigned short* __restrict__ u,
                                                  const float* __restrict__ BC,
                                                  const float* __restrict__ A_log,
                                                  const int* __restrict__ flag,
                                                  float* __restrict__ hloc,
                                                  float* __restrict__ dsum) {
  const int b = blockIdx.y, c = blockIdx.z;
  const int d = blockIdx.x * 256 + threadIdx.x;
  const int fast = flag[0];
  const size_t mbase = (size_t)(b * L_ + c * TC);
  const unsigned short* dp = delta + mbase * DI + d;
  const unsigned short* up = u + mbase * DI + d;
  const float* bc = BC + mbase * 32;
  float h[16];
#pragma unroll
  for (int s = 0; s < 16; s++) h[s] = 0.f;
  float sd = 0.f;
  if (fast) {
    const float As0 = -__expf(A_log[(size_t)d * 16]);
    for (int t8 = 0; t8 < TC; t8 += 8) {
      float dv[8], uvf[8];
#pragma unroll
      for (int i = 0; i < 8; i++) dv[i] = bf2f(dp[(size_t)(t8 + i) * DI]);
#pragma unroll
      for (int i = 0; i < 8; i++) uvf[i] = bf2f(up[(size_t)(t8 + i) * DI]);
#pragma unroll
      for (int i = 0; i < 8; i++) {
        const float dvi = dv[i];
        const float w = dvi * uvf[i];
        sd += dvi;
        const float* bct = bc + (size_t)(t8 + i) * 32;
        const float a1 = __expf(dvi * As0);
        float pp = 1.f;   // incremental power: 1 register, consumed ascending
#pragma unroll
        for (int q = 0; q < 4; q++) {
          const f32x4 bq = *(const f32x4*)(bct + q * 4);
#pragma unroll
          for (int j = 0; j < 4; j++) {
            const int s = q * 4 + j;
            pp *= a1;
            h[s] = pp * h[s] + w * bq[j];
          }
        }
      }
    }
  } else {
    float As[16];
#pragma unroll
    for (int q = 0; q < 4; q++) {
      const f32x4 av = *(const f32x4*)(A_log + (size_t)d * 16 + q * 4);
#pragma unroll
      for (int j = 0; j < 4; j++) As[q * 4 + j] = -__expf(av[j]);
    }
    for (int t8 = 0; t8 < TC; t8 += 8) {
      float dv[8], uvf[8];
#pragma unroll
      for (int i = 0; i < 8; i++) dv[i] = bf2f(dp[(size_t)(t8 + i) * DI]);
#pragma unroll
      for (int i = 0; i < 8; i++) uvf[i] = bf2f(up[(size_t)(t8 + i) * DI]);
#pragma unroll
      for (int i = 0; i < 8; i++) {
        const float dvi = dv[i];
        const float w = dvi * uvf[i];
        sd += dvi;
        const float* bct = bc + (size_t)(t8 + i) * 32;
#pragma unroll
        for (int q = 0; q < 4; q++) {
          const f32x4 bq = *(const f32x4*)(bct + q * 4);
#pragma unroll
          for (int j = 0; j < 4; j++) {
            const int s = q * 4 + j;
            h[s] = __expf(dvi * As[s]) * h[s] + w * bq[j];
          }
        }
      }
    }
  }
  float* hl = hloc + (((size_t)(b * NC + c)) * DI + d) * 16;
#pragma unroll
  for (int q = 0; q < 4; q++) {
    f32x4 v = {h[q * 4], h[q * 4 + 1], h[q * 4 + 2], h[q * 4 + 3]};
    *(f32x4*)(hl + q * 4) = v;
  }
  dsum[((size_t)(b * NC + c)) * DI + d] = sd;
}

// =================== scan phase B: chunk prefix per (b,d) ===================
__global__ __launch_bounds__(256) void k_scanB(const float* __restrict__ hloc,
                                               const float* __restrict__ dsum,
                                               const float* __restrict__ A_log,
                                               const int* __restrict__ flag,
                                               float* __restrict__ hin) {
  const int i = blockIdx.x * 256 + threadIdx.x;   // 8192 = B*DI
  const int b = i >> 11, d = i & 2047;
  const int fast = flag[0];
  float As[16];
  const float As0 = -__expf(A_log[(size_t)d * 16]);
  if (!fast) {
#pragma unroll
    for (int q = 0; q < 4; q++) {
      const f32x4 av = *(const f32x4*)(A_log + (size_t)d * 16 + q * 4);
#pragma unroll
      for (int j = 0; j < 4; j++) As[q * 4 + j] = -__expf(av[j]);
    }
  }
  float H[16];
#pragma unroll
  for (int s = 0; s < 16; s++) H[s] = 0.f;
  for (int c = 0; c < NC; c++) {
    float* hp = hin + (((size_t)(b * NC + c)) * DI + d) * 16;
#pragma unroll
    for (int q = 0; q < 4; q++) {
      f32x4 v = {H[q * 4], H[q * 4 + 1], H[q * 4 + 2], H[q * 4 + 3]};
      *(f32x4*)(hp + q * 4) = v;
    }
    if (c < NC - 1) {
      const float sd = dsum[((size_t)(b * NC + c)) * DI + d];
      const float* hl = hloc + (((size_t)(b * NC + c)) * DI + d) * 16;
      if (fast) {
        const float a1 = __expf(sd * As0);
        float pp = 1.f;
#pragma unroll
        for (int s = 0; s < 16; s++) { pp *= a1; H[s] = pp * H[s] + hl[s]; }
      } else {
#pragma unroll
        for (int s = 0; s < 16; s++) H[s] = __expf(sd * As[s]) * H[s] + hl[s];
      }
    }
  }
}

// =================== scan phase C: apply carry, y = C.h, fused skip + silu(z) gate ===================
__global__ __launch_bounds__(256, 4) void k_scanC(const unsigned short* __restrict__ delta,
                                                  const unsigned short* __restrict__ u,
                                                  const unsigned short* __restrict__ z,
                                                  const float* __restrict__ BC,
                                                  const float* __restrict__ A_log,
                                                  const float* __restrict__ Dsk,
                                                  const int* __restrict__ flag,
                                                  const float* __restrict__ hin,
                                                  unsigned short* __restrict__ y) {
  const int b = blockIdx.y, c = blockIdx.z;
  const int d = blockIdx.x * 256 + threadIdx.x;
  const int fast = flag[0];
  const size_t mbase = (size_t)(b * L_ + c * TC);
  const unsigned short* dp = delta + mbase * DI + d;
  const unsigned short* up = u + mbase * DI + d;
  const unsigned short* zp = z + mbase * DI + d;
  const float* bc = BC + mbase * 32;
  const float dsk = Dsk[d];
  float h[16];
  const float* hp = hin + (((size_t)(b * NC + c)) * DI + d) * 16;
#pragma unroll
  for (int q = 0; q < 4; q++) {
    const f32x4 v = *(const f32x4*)(hp + q * 4);
#pragma unroll
    for (int j = 0; j < 4; j++) h[q * 4 + j] = v[j];
  }
  unsigned short* yp = y + mbase * DI + d;
  if (fast) {
    const float As0 = -__expf(A_log[(size_t)d * 16]);
    for (int t8 = 0; t8 < TC; t8 += 8) {
      float dv[8], uvf[8], zvf[8];
#pragma unroll
      for (int i = 0; i < 8; i++) dv[i] = bf2f(dp[(size_t)(t8 + i) * DI]);
#pragma unroll
      for (int i = 0; i < 8; i++) uvf[i] = bf2f(up[(size_t)(t8 + i) * DI]);
#pragma unroll
      for (int i = 0; i < 8; i++) zvf[i] = bf2f(zp[(size_t)(t8 + i) * DI]);
#pragma unroll
      for (int i = 0; i < 8; i++) {
        const float dvi = dv[i];
        const float w = dvi * uvf[i];
        const float* bct = bc + (size_t)(t8 + i) * 32;
        const float a1 = __expf(dvi * As0);
        float pp = 1.f;
        float y0 = 0.f, y1 = 0.f;
#pragma unroll
        for (int q = 0; q < 4; q++) {
          const f32x4 bq = *(const f32x4*)(bct + q * 4);
          const f32x4 cq = *(const f32x4*)(bct + 16 + q * 4);
#pragma unroll
          for (int j = 0; j < 4; j++) {
            const int s = q * 4 + j;
            pp *= a1;
            h[s] = pp * h[s] + w * bq[j];
            if (j & 1) y1 += h[s] * cq[j]; else y0 += h[s] * cq[j];
          }
        }
        const float yt = (y0 + y1 + uvf[i] * dsk) * silu_f(zvf[i]);
        yp[(size_t)(t8 + i) * DI] = f2bf(yt);
      }
    }
  } else {
    float As[16];
#pragma unroll
    for (int q = 0; q < 4; q++) {
      const f32x4 av = *(const f32x4*)(A_log + (size_t)d * 16 + q * 4);
#pragma unroll
      for (int j = 0; j < 4; j++) As[q * 4 + j] = -__expf(av[j]);
    }
    for (int t8 = 0; t8 < TC; t8 += 8) {
      float dv[8], uvf[8], zvf[8];
#pragma unroll
      for (int i = 0; i < 8; i++) dv[i] = bf2f(dp[(size_t)(t8 + i) * DI]);
#pragma unroll
      for (int i = 0; i < 8; i++) uvf[i] = bf2f(up[(size_t)(t8 + i) * DI]);
#pragma unroll
      for (int i = 0; i < 8; i++) zvf[i] = bf2f(zp[(size_t)(t8 + i) * DI]);
#pragma unroll
      for (int i = 0; i < 8; i++) {
        const float dvi = dv[i];
        const float w = dvi * uvf[i];
        const float* bct = bc + (size_t)(t8 + i) * 32;
        float y0 = 0.f, y1 = 0.f;
#pragma unroll
        for (int q = 0; q < 4; q++) {
          const f32x4 bq = *(const f32x4*)(bct + q * 4);
          const f32x4 cq = *(const f32x4*)(bct + 16 + q * 4);
#pragma unroll
          for (int j = 0; j < 4; j++) {
            const int s = q * 4 + j;
            h[s] = __expf(dvi * As[s]) * h[s] + w * bq[j];
            if (j & 1) y1 += h[s] * cq[j]; else y0 += h[s] * cq[j];
          }
        }
        const float yt = (y0 + y1 + uvf[i] * dsk) * silu_f(zvf[i]);
        yp[(size_t)(t8 + i) * DI] = f2bf(yt);
      }
    }
  }
}

// =================== launch ===================
extern "C" void kernel_launch(void* const* d_in, const int* in_sizes, int n_in,
                              void* d_out, int out_size, void* d_ws, size_t ws_size,
                              hipStream_t stream) {
  const float* x      = (const float*)d_in[0];
  const float* c      = (const float*)d_in[1];
  const float* W_in   = (const float*)d_in[2];
  const float* conv_w = (const float*)d_in[3];
  const float* conv_b = (const float*)d_in[4];
  const float* W_xp   = (const float*)d_in[5];
  const float* W_dt   = (const float*)d_in[6];
  const float* b_dt   = (const float*)d_in[7];
  const float* A_log  = (const float*)d_in[8];
  const float* D_skip = (const float*)d_in[9];
  const float* W_out  = (const float*)d_in[10];
  const float* W_ada  = (const float*)d_in[11];
  const float* b_ada  = (const float*)d_in[12];
  float* out = (float*)d_out;

  char* ws = (char*)d_ws;
  size_t off = 0;
  auto take = [&](size_t bytes) {
    char* p = ws + off;
    off += (bytes + 255) & ~(size_t)255;
    return p;
  };
  float* mod             = (float*)take((size_t)4 * 3072 * 4);
  unsigned short* Wt_in  = (unsigned short*)take((size_t)4096 * 1024 * 2);
  unsigned short* Wt_out = (unsigned short*)take((size_t)1024 * 2048 * 2);
  unsigned short* Wt_xp  = (unsigned short*)take((size_t)128 * 2048 * 2);
  unsigned short* Wt_dt  = (unsigned short*)take((size_t)2048 * 64 * 2);
  unsigned short* h_bf   = (unsigned short*)take((size_t)8192 * 1024 * 2);      // 16MB; then part_T, then hin
  unsigned short* xm     = (unsigned short*)take((size_t)4 * 2048 * 2048 * 2);  // 32MB [m][d]; then y_bf
  unsigned short* z_bf   = (unsigned short*)take((size_t)4 * 2048 * 2048 * 2);  // 32MB [m][d]
  unsigned short* scanws = (unsigned short*)take((size_t)4 * 2048 * 2048 * 2);  // 32MB; hloc(16MB)+dsum(1MB)
  unsigned short* u_bf   = (unsigned short*)take((size_t)8192 * 2048 * 2);      // 32MB [m][d]; u==xc
  unsigned short* delta  = (unsigned short*)take((size_t)8192 * 2048 * 2);      // 32MB [m][d] bf16
  unsigned short* dt_bf  = (unsigned short*)take((size_t)8192 * 64 * 2);
  float* BC              = (float*)take((size_t)4 * 2048 * 32 * 4);             // [m][32]: B|C packed
  int* flag              = (int*)take(256);
  float* part_T = (float*)h_bf;                                   // dead after k_xsplit
  float* hin    = (float*)h_bf;                                   // 16MB exact; written by scanB
  float* hloc   = (float*)scanws;                                 // 16MB
  float* dsum   = (float*)(scanws + (size_t)8 * 1024 * 1024);     // +16MB, 1MB
  unsigned short* y_bf = xm;                                      // xm dead after conv

  // 0. A-structure check (enables scan exp-chain fast path)
  k_chk<<<1, 256, 0, stream>>>(A_log, flag);
  // 1. fused pre-pass: weight transpose x4 + ada GEMM (6528 + 48 blocks)
  k_pre<<<6576, 256, 0, stream>>>(W_in, Wt_in, W_out, Wt_out, W_xp, Wt_xp, W_dt, Wt_dt,
                                  c, W_ada, b_ada, mod);
  // 2. LN + modulation
  k_ln<<<8192, 256, 0, stream>>>(x, mod, h_bf);
  // 3. in-proj -> xm[m][d], z[m][d]
  GArgs a1{h_bf, Wt_in, 1024, 1024, 1024, nullptr, xm, z_bf, nullptr, nullptr};
  k_gemm<0><<<dim3(64, 32), 256, 0, stream>>>(a1);
  // 4. conv + silu -> u[m][d]
  k_conv<<<dim3(64, 32, 4), 256, 0, stream>>>(xm, conv_w, conv_b, u_bf);
  // 5. x-proj (split-K)
  GArgs a2{u_bf, Wt_xp, 2048, 2048, 512, part_T, nullptr, nullptr, nullptr, nullptr};
  k_gemm<1><<<dim3(64, 1, 4), 256, 0, stream>>>(a2);
  // 6. reduce + split (dt rows; BC[m][32])
  k_xsplit<<<3072, 256, 0, stream>>>(part_T, dt_bf, BC);
  // 7. dt-proj + softplus -> delta[m][d] bf16
  GArgs a3{dt_bf, Wt_dt, 64, 64, 64, nullptr, delta, nullptr, b_dt, nullptr};
  k_gemm<2><<<dim3(64, 16), 256, 0, stream>>>(a3);
  // 8. chunked selective scan, [m][d] coalesced, incremental exp-chain fast path
  k_scanA<<<dim3(8, 4, NC - 1), 256, 0, stream>>>(delta, u_bf, BC, A_log, flag, hloc, dsum);
  k_scanB<<<32, 256, 0, stream>>>(hloc, dsum, A_log, flag, hin);
  k_scanC<<<dim3(8, 4, NC), 256, 0, stream>>>(delta, u_bf, z_bf, BC, A_log, D_skip, flag, hin, y_bf);
  // 9. out-proj + residual + gate
  GArgs a4{y_bf, Wt_out, 2048, 2048, 2048, out, nullptr, nullptr, x, mod};
  k_gemm<3><<<dim3(64, 8), 256, 0, stream>>>(a4);
}

// Round 10
// 524.265 us; speedup vs baseline: 1.3629x; 1.1677x over previous
//
#include <hip/hip_runtime.h>
#include <hip/hip_bf16.h>
#include <stdint.h>

// MambaConditioningBlock on gfx950.
// B=4, L=2048, D_MODEL=1024, D_INNER=2048, D_STATE=16, DT_RANK=64, D_CONV=4.
// R10: k_pre was 91us with GPU idle (VALUBusy 4%) - the 48-block ada GEMM tail
// is latency-bound (1 wave/SIMD, serial K=1024 strided loads). Fix: K-split 8x
// (384 blocks, atomicAdd partials; bias pre-seeded by k_chk blocks 1..48),
// ada blocks placed FIRST in the flat grid to overlap the transpose blocks.

#define L_ 2048
#define DM 1024
#define DI 2048
#define DS 16
#define NC 32    // scan chunks
#define TC 64    // steps per chunk

typedef __bf16 bf16x8 __attribute__((ext_vector_type(8)));
typedef float f32x4 __attribute__((ext_vector_type(4)));

__device__ __forceinline__ float bf2f(unsigned int u) {
  union { unsigned int i; float f; } c;
  c.i = (u & 0xFFFFu) << 16;
  return c.f;
}
__device__ __forceinline__ unsigned short f2bf(float f) {
  union { float f; unsigned int i; } c; c.f = f;
  unsigned int x = c.i;
  return (unsigned short)((x + 0x7FFFu + ((x >> 16) & 1u)) >> 16);  // RNE
}
__device__ __forceinline__ float silu_f(float v) { return v / (1.f + __expf(-v)); }

// ---- async global->LDS, 16B per lane ----
__device__ __forceinline__ void async_cp16(unsigned short* lds, const unsigned short* g) {
  __builtin_amdgcn_global_load_lds(
      (const __attribute__((address_space(1))) unsigned int*)g,
      (__attribute__((address_space(3))) unsigned int*)lds, 16, 0, 0);
}

// =================== block 0: A-structure check; blocks 1..48: seed mod with bias ===================
__global__ __launch_bounds__(256) void k_chk(const float* __restrict__ A_log,
                                             int* __restrict__ flag,
                                             const float* __restrict__ b_ada,
                                             float* __restrict__ mod) {
  if (blockIdx.x > 0) {
    const int i = (blockIdx.x - 1) * 256 + threadIdx.x;   // 0..12287
    mod[i] = b_ada[i % 3072];
    return;
  }
  __shared__ int ok;
  if (threadIdx.x == 0) ok = 1;
  __syncthreads();
  int good = 1;
  for (int i = threadIdx.x; i < DI * DS; i += 256) {
    const int s = i & 15, d = i >> 4;
    const float a = __expf(A_log[i]);
    const float expect = __expf(A_log[d * 16]) * (float)(s + 1);
    if (fabsf(a - expect) > 1e-4f * expect) good = 0;
  }
  if (!good) atomicAnd(&ok, 0);
  __syncthreads();
  if (threadIdx.x == 0) flag[0] = ok;
}

// =================== fused pre-pass: ada GEMM (K-split) + 4x weight transpose ===================
// blocks [0,384): ada partial K=128, atomicAdd into mod (pre-seeded with bias).
// blocks [384,6912): src[K][N] fp32 -> dst[NP][K] bf16 transposes.
__global__ __launch_bounds__(256) void k_pre(const float* __restrict__ s0, unsigned short* __restrict__ d0,
                                             const float* __restrict__ s1, unsigned short* __restrict__ d1,
                                             const float* __restrict__ s2, unsigned short* __restrict__ d2,
                                             const float* __restrict__ s3, unsigned short* __restrict__ d3,
                                             const float* __restrict__ cvec,
                                             const float* __restrict__ W_ada,
                                             float* __restrict__ mod) {
  __shared__ float tile[32][33];   // ada branch reuses as sck[128]
  int bid = blockIdx.x;
  const int tid = threadIdx.x;
  if (bid < 384) {  // ada: mod[b][j] += sum_{k in chunk} silu(c[b][k]) * W_ada[k][j]
    const int b = bid & 3;
    const int t2 = bid >> 2;           // 0..95
    const int jb = t2 % 12;            // 0..11
    const int kc = t2 / 12;            // 0..7
    float* sck = &tile[0][0];
    const int k0 = kc * 128;
    if (tid < 128) sck[tid] = silu_f(cvec[b * DM + k0 + tid]);
    __syncthreads();
    const int j = jb * 256 + tid;
    float acc = 0.f;
#pragma unroll 8
    for (int k = 0; k < 128; k++) acc += sck[k] * W_ada[(size_t)(k0 + k) * 3072 + j];
    atomicAdd(&mod[b * 3072 + j], acc);
    return;
  }
  bid -= 384;
  const float* src; unsigned short* dst; int K, N, NP, kb, nb;
  if (bid < 4096)                { src = s0; dst = d0; K = 1024; N = 4096; NP = 4096; kb = bid & 31; nb = bid >> 5; }
  else if ((bid -= 4096) < 2048) { src = s1; dst = d1; K = 2048; N = 1024; NP = 1024; kb = bid & 63; nb = bid >> 6; }
  else if ((bid -= 2048) < 256)  { src = s2; dst = d2; K = 2048; N = 96;   NP = 128;  kb = bid & 63; nb = bid >> 6; }
  else { bid -= 256;               src = s3; dst = d3; K = 64;   N = 2048; NP = 2048; kb = bid & 1;  nb = bid >> 1; }
  const int kb0 = kb * 32, nb0 = nb * 32;
  const int tx = tid & 31, ty = tid >> 5;
#pragma unroll
  for (int i = 0; i < 4; i++) {
    int k = kb0 + ty + 8 * i, n = nb0 + tx;
    float v = 0.f;
    if (k < K && n < N) v = src[(size_t)k * N + n];
    tile[ty + 8 * i][tx] = v;
  }
  __syncthreads();
#pragma unroll
  for (int i = 0; i < 4; i++) {
    int n = nb0 + ty + 8 * i, k = kb0 + tx;
    if (n < NP && k < K) dst[(size_t)n * K + k] = f2bf(tile[tx][ty + 8 * i]);
  }
}

// =================== LayerNorm + adaLN modulation -> bf16 ===================
__global__ __launch_bounds__(256) void k_ln(const float* __restrict__ x,
                                            const float* __restrict__ mod,
                                            unsigned short* __restrict__ h) {
  const int row = blockIdx.x, b = row >> 11, tid = threadIdx.x;
  const float4 v = ((const float4*)(x + (size_t)row * DM))[tid];
  float s = v.x + v.y + v.z + v.w;
  float ss = v.x * v.x + v.y * v.y + v.z * v.z + v.w * v.w;
#pragma unroll
  for (int off = 32; off; off >>= 1) { s += __shfl_down(s, off); ss += __shfl_down(ss, off); }
  __shared__ float red[10];
  const int wv = tid >> 6, ln = tid & 63;
  if (ln == 0) { red[wv] = s; red[4 + wv] = ss; }
  __syncthreads();
  if (tid == 0) {
    float st = red[0] + red[1] + red[2] + red[3];
    float sst = red[4] + red[5] + red[6] + red[7];
    float mu = st * (1.f / DM);
    red[8] = mu;
    red[9] = rsqrtf(sst * (1.f / DM) - mu * mu + 1e-6f);
  }
  __syncthreads();
  const float mu = red[8], rstd = red[9];
  const int ccol = tid * 4;
  const float4 sc = *(const float4*)(mod + b * 3072 + ccol);
  const float4 sh = *(const float4*)(mod + b * 3072 + DM + ccol);
  uint2 p;
  p.x = (unsigned)f2bf((v.x - mu) * rstd * (1.f + sc.x) + sh.x) |
        ((unsigned)f2bf((v.y - mu) * rstd * (1.f + sc.y) + sh.y) << 16);
  p.y = (unsigned)f2bf((v.z - mu) * rstd * (1.f + sc.z) + sh.z) |
        ((unsigned)f2bf((v.w - mu) * rstd * (1.f + sc.w) + sh.w) << 16);
  *(uint2*)(h + (size_t)row * DM + ccol) = p;
}

// =================== bf16 MFMA GEMM, 128x128 tile, m97 structure ===================
struct GArgs {
  const unsigned short* A;
  const unsigned short* Bt;
  int lda, ldb, klen;
  float* f0;
  unsigned short* h0;
  unsigned short* h1;
  const float* c0;
  const float* c1;
};

template<int EPI>
__global__ __launch_bounds__(256, 2) void k_gemm(GArgs g) {
  __shared__ unsigned short sA[128 * 32];
  __shared__ unsigned short sB[128 * 32];
  const int tid = threadIdx.x;
  const int w = tid >> 6, lane = tid & 63;
  const int m0 = blockIdx.x * 128, n0 = blockIdx.y * 128;
  const int kstart = blockIdx.z * g.klen;
  const int r4 = lane >> 2;
  const int c8 = (lane & 3) * 8;
  const int rowA0 = w * 16 + r4, rowA1 = (w + 4) * 16 + r4;
  const unsigned short* gA0 = g.A + (size_t)(m0 + rowA0) * g.lda + kstart + c8;
  const unsigned short* gA1 = g.A + (size_t)(m0 + rowA1) * g.lda + kstart + c8;
  const unsigned short* gB0 = g.Bt + (size_t)(n0 + rowA0) * g.ldb + kstart + c8;
  const unsigned short* gB1 = g.Bt + (size_t)(n0 + rowA1) * g.ldb + kstart + c8;
  unsigned short* lA0 = sA + w * 512;
  unsigned short* lA1 = sA + (w + 4) * 512;
  unsigned short* lB0 = sB + w * 512;
  unsigned short* lB1 = sB + (w + 4) * 512;
  const int mw = (w & 1) * 64, nw = (w >> 1) * 64;
  const int row16 = lane & 15, k8 = (lane >> 4) * 8;
  f32x4 acc[4][4] = {};
  for (int kk = 0; kk < g.klen; kk += 32) {
    async_cp16(lA0, gA0); async_cp16(lA1, gA1);
    async_cp16(lB0, gB0); async_cp16(lB1, gB1);
    gA0 += 32; gA1 += 32; gB0 += 32; gB1 += 32;
    __syncthreads();
    bf16x8 av[4], bv[4];
#pragma unroll
    for (int i = 0; i < 4; i++)
      av[i] = *(const bf16x8*)(sA + (mw + 16 * i + row16) * 32 + k8);
#pragma unroll
    for (int j = 0; j < 4; j++)
      bv[j] = *(const bf16x8*)(sB + (nw + 16 * j + row16) * 32 + k8);
#pragma unroll
    for (int i = 0; i < 4; i++)
#pragma unroll
      for (int j = 0; j < 4; j++)
        acc[i][j] = __builtin_amdgcn_mfma_f32_16x16x32_bf16(av[i], bv[j], acc[i][j], 0, 0, 0);
    __syncthreads();
  }
  const int qr = (lane >> 4) * 4, cn = lane & 15;
#pragma unroll
  for (int i = 0; i < 4; i++) {
    const int m = m0 + mw + 16 * i + qr;
    const int b = m >> 11;
#pragma unroll
    for (int j = 0; j < 4; j++) {
      const int n = n0 + nw + 16 * j + cn;
      f32x4 v = acc[i][j];
      if constexpr (EPI == 0) {
#pragma unroll
        for (int r = 0; r < 4; r++) {
          unsigned short* dst = (n < DI)
              ? g.h0 + (size_t)(m + r) * DI + n
              : g.h1 + (size_t)(m + r) * DI + (n - DI);
          *dst = f2bf(v[r]);
        }
      } else if constexpr (EPI == 1) {
        *(f32x4*)(g.f0 + ((size_t)(blockIdx.z * 128 + n)) * 8192 + m) = v;
      } else if constexpr (EPI == 2) {
        const float bn = g.c0[n];
#pragma unroll
        for (int r = 0; r < 4; r++) {
          float xx = v[r] + bn;
          g.h0[(size_t)(m + r) * DI + n] = f2bf((xx > 15.f) ? xx : __logf(1.f + __expf(xx)));
        }
      } else {
        const float gate = g.c1[b * 3072 + 2048 + n];
#pragma unroll
        for (int r = 0; r < 4; r++) {
          size_t idx = (size_t)(m + r) * DM + n;
          g.f0[idx] = g.c0[idx] + gate * v[r];
        }
      }
    }
  }
}

// =================== causal depthwise conv (k=4) + silu, [m][d] -> [m][d] ===================
__global__ __launch_bounds__(256) void k_conv(const unsigned short* __restrict__ xm,
                                              const float* __restrict__ conv_w,
                                              const float* __restrict__ conv_b,
                                              unsigned short* __restrict__ u) {
  const int b = blockIdx.z;
  const int t = blockIdx.x * 32 + (threadIdx.x >> 3);
  const int d = blockIdx.y * 64 + (threadIdx.x & 7) * 8;
  const size_t rowbase = ((size_t)(b * L_ + t)) * DI + d;
  uint4 r3 = *(const uint4*)(xm + rowbase);
  uint4 r0 = make_uint4(0, 0, 0, 0), r1 = r0, r2 = r0;
  if (t >= 3) r0 = *(const uint4*)(xm + rowbase - 3 * DI);
  if (t >= 2) r1 = *(const uint4*)(xm + rowbase - 2 * DI);
  if (t >= 1) r2 = *(const uint4*)(xm + rowbase - 1 * DI);
  float x0[8], x1[8], x2[8], x3[8];
  const unsigned* p0 = (const unsigned*)&r0;
  const unsigned* p1 = (const unsigned*)&r1;
  const unsigned* p2 = (const unsigned*)&r2;
  const unsigned* p3 = (const unsigned*)&r3;
#pragma unroll
  for (int q = 0; q < 4; q++) {
    x0[2 * q] = bf2f(p0[q]); x0[2 * q + 1] = bf2f(p0[q] >> 16);
    x1[2 * q] = bf2f(p1[q]); x1[2 * q + 1] = bf2f(p1[q] >> 16);
    x2[2 * q] = bf2f(p2[q]); x2[2 * q + 1] = bf2f(p2[q] >> 16);
    x3[2 * q] = bf2f(p3[q]); x3[2 * q + 1] = bf2f(p3[q] >> 16);
  }
  const f32x4 cb0 = *(const f32x4*)(conv_b + d);
  const f32x4 cb1 = *(const f32x4*)(conv_b + d + 4);
  unsigned out[4];
#pragma unroll
  for (int j = 0; j < 8; j++) {
    const f32x4 wj = *(const f32x4*)(conv_w + (size_t)(d + j) * 4);
    const float cb = (j < 4) ? cb0[j] : cb1[j - 4];
    float a = cb + wj[0] * x0[j] + wj[1] * x1[j] + wj[2] * x2[j] + wj[3] * x3[j];
    unsigned short us = f2bf(silu_f(a));
    if (j & 1) out[j >> 1] |= ((unsigned)us << 16);
    else out[j >> 1] = us;
  }
  *(uint4*)(u + rowbase) = make_uint4(out[0], out[1], out[2], out[3]);
}

// =================== reduce split-K partials, split dt / pack BC[m][32] ===================
__global__ __launch_bounds__(256) void k_xsplit(const float* __restrict__ pt,
                                                unsigned short* __restrict__ dtb,
                                                float* __restrict__ BC) {
  const int bx = blockIdx.x;
  const int n = bx >> 5;
  const int m = ((bx & 31) << 8) + threadIdx.x;
  float v = pt[(size_t)n * 8192 + m] + pt[(size_t)(128 + n) * 8192 + m] +
            pt[(size_t)(256 + n) * 8192 + m] + pt[(size_t)(384 + n) * 8192 + m];
  if (n < 64) dtb[(size_t)m * 64 + n] = f2bf(v);
  else if (n < 80) BC[(size_t)m * 32 + (n - 64)] = v;
  else BC[(size_t)m * 32 + 16 + (n - 80)] = v;
}

// =================== scan phase A: local chunk scan, emit h_loc[16] + sum(delta) ===================
__global__ __launch_bounds__(256, 4) void k_scanA(const unsigned short* __restrict__ delta,
                                                  const unsigned short* __restrict__ u,
                                                  const float* __restrict__ BC,
                                                  const float* __restrict__ A_log,
                                                  const int* __restrict__ flag,
                                                  float* __restrict__ hloc,
                                                  float* __restrict__ dsum) {
  const int b = blockIdx.y, c = blockIdx.z;
  const int d = blockIdx.x * 256 + threadIdx.x;
  const int fast = flag[0];
  const size_t mbase = (size_t)(b * L_ + c * TC);
  const unsigned short* dp = delta + mbase * DI + d;
  const unsigned short* up = u + mbase * DI + d;
  const float* bc = BC + mbase * 32;
  float h[16];
#pragma unroll
  for (int s = 0; s < 16; s++) h[s] = 0.f;
  float sd = 0.f;
  if (fast) {
    const float As0 = -__expf(A_log[(size_t)d * 16]);
    for (int t8 = 0; t8 < TC; t8 += 8) {
      float dv[8], uvf[8];
#pragma unroll
      for (int i = 0; i < 8; i++) dv[i] = bf2f(dp[(size_t)(t8 + i) * DI]);
#pragma unroll
      for (int i = 0; i < 8; i++) uvf[i] = bf2f(up[(size_t)(t8 + i) * DI]);
#pragma unroll
      for (int i = 0; i < 8; i++) {
        const float dvi = dv[i];
        const float w = dvi * uvf[i];
        sd += dvi;
        const float* bct = bc + (size_t)(t8 + i) * 32;
        const float a1 = __expf(dvi * As0);
        float pp = 1.f;
#pragma unroll
        for (int q = 0; q < 4; q++) {
          const f32x4 bq = *(const f32x4*)(bct + q * 4);
#pragma unroll
          for (int j = 0; j < 4; j++) {
            const int s = q * 4 + j;
            pp *= a1;
            h[s] = pp * h[s] + w * bq[j];
          }
        }
      }
    }
  } else {
    float As[16];
#pragma unroll
    for (int q = 0; q < 4; q++) {
      const f32x4 av = *(const f32x4*)(A_log + (size_t)d * 16 + q * 4);
#pragma unroll
      for (int j = 0; j < 4; j++) As[q * 4 + j] = -__expf(av[j]);
    }
    for (int t8 = 0; t8 < TC; t8 += 8) {
      float dv[8], uvf[8];
#pragma unroll
      for (int i = 0; i < 8; i++) dv[i] = bf2f(dp[(size_t)(t8 + i) * DI]);
#pragma unroll
      for (int i = 0; i < 8; i++) uvf[i] = bf2f(up[(size_t)(t8 + i) * DI]);
#pragma unroll
      for (int i = 0; i < 8; i++) {
        const float dvi = dv[i];
        const float w = dvi * uvf[i];
        sd += dvi;
        const float* bct = bc + (size_t)(t8 + i) * 32;
#pragma unroll
        for (int q = 0; q < 4; q++) {
          const f32x4 bq = *(const f32x4*)(bct + q * 4);
#pragma unroll
          for (int j = 0; j < 4; j++) {
            const int s = q * 4 + j;
            h[s] = __expf(dvi * As[s]) * h[s] + w * bq[j];
          }
        }
      }
    }
  }
  float* hl = hloc + (((size_t)(b * NC + c)) * DI + d) * 16;
#pragma unroll
  for (int q = 0; q < 4; q++) {
    f32x4 v = {h[q * 4], h[q * 4 + 1], h[q * 4 + 2], h[q * 4 + 3]};
    *(f32x4*)(hl + q * 4) = v;
  }
  dsum[((size_t)(b * NC + c)) * DI + d] = sd;
}

// =================== scan phase B: chunk prefix per (b,d) ===================
__global__ __launch_bounds__(256) void k_scanB(const float* __restrict__ hloc,
                                               const float* __restrict__ dsum,
                                               const float* __restrict__ A_log,
                                               const int* __restrict__ flag,
                                               float* __restrict__ hin) {
  const int i = blockIdx.x * 256 + threadIdx.x;   // 8192 = B*DI
  const int b = i >> 11, d = i & 2047;
  const int fast = flag[0];
  float As[16];
  const float As0 = -__expf(A_log[(size_t)d * 16]);
  if (!fast) {
#pragma unroll
    for (int q = 0; q < 4; q++) {
      const f32x4 av = *(const f32x4*)(A_log + (size_t)d * 16 + q * 4);
#pragma unroll
      for (int j = 0; j < 4; j++) As[q * 4 + j] = -__expf(av[j]);
    }
  }
  float H[16];
#pragma unroll
  for (int s = 0; s < 16; s++) H[s] = 0.f;
  for (int c = 0; c < NC; c++) {
    float* hp = hin + (((size_t)(b * NC + c)) * DI + d) * 16;
#pragma unroll
    for (int q = 0; q < 4; q++) {
      f32x4 v = {H[q * 4], H[q * 4 + 1], H[q * 4 + 2], H[q * 4 + 3]};
      *(f32x4*)(hp + q * 4) = v;
    }
    if (c < NC - 1) {
      const float sd = dsum[((size_t)(b * NC + c)) * DI + d];
      const float* hl = hloc + (((size_t)(b * NC + c)) * DI + d) * 16;
      if (fast) {
        const float a1 = __expf(sd * As0);
        float pp = 1.f;
#pragma unroll
        for (int s = 0; s < 16; s++) { pp *= a1; H[s] = pp * H[s] + hl[s]; }
      } else {
#pragma unroll
        for (int s = 0; s < 16; s++) H[s] = __expf(sd * As[s]) * H[s] + hl[s];
      }
    }
  }
}

// =================== scan phase C: apply carry, y = C.h, fused skip + silu(z) gate ===================
__global__ __launch_bounds__(256, 4) void k_scanC(const unsigned short* __restrict__ delta,
                                                  const unsigned short* __restrict__ u,
                                                  const unsigned short* __restrict__ z,
                                                  const float* __restrict__ BC,
                                                  const float* __restrict__ A_log,
                                                  const float* __restrict__ Dsk,
                                                  const int* __restrict__ flag,
                                                  const float* __restrict__ hin,
                                                  unsigned short* __restrict__ y) {
  const int b = blockIdx.y, c = blockIdx.z;
  const int d = blockIdx.x * 256 + threadIdx.x;
  const int fast = flag[0];
  const size_t mbase = (size_t)(b * L_ + c * TC);
  const unsigned short* dp = delta + mbase * DI + d;
  const unsigned short* up = u + mbase * DI + d;
  const unsigned short* zp = z + mbase * DI + d;
  const float* bc = BC + mbase * 32;
  const float dsk = Dsk[d];
  float h[16];
  const float* hp = hin + (((size_t)(b * NC + c)) * DI + d) * 16;
#pragma unroll
  for (int q = 0; q < 4; q++) {
    const f32x4 v = *(const f32x4*)(hp + q * 4);
#pragma unroll
    for (int j = 0; j < 4; j++) h[q * 4 + j] = v[j];
  }
  unsigned short* yp = y + mbase * DI + d;
  if (fast) {
    const float As0 = -__expf(A_log[(size_t)d * 16]);
    for (int t8 = 0; t8 < TC; t8 += 8) {
      float dv[8], uvf[8], zvf[8];
#pragma unroll
      for (int i = 0; i < 8; i++) dv[i] = bf2f(dp[(size_t)(t8 + i) * DI]);
#pragma unroll
      for (int i = 0; i < 8; i++) uvf[i] = bf2f(up[(size_t)(t8 + i) * DI]);
#pragma unroll
      for (int i = 0; i < 8; i++) zvf[i] = bf2f(zp[(size_t)(t8 + i) * DI]);
#pragma unroll
      for (int i = 0; i < 8; i++) {
        const float dvi = dv[i];
        const float w = dvi * uvf[i];
        const float* bct = bc + (size_t)(t8 + i) * 32;
        const float a1 = __expf(dvi * As0);
        float pp = 1.f;
        float y0 = 0.f, y1 = 0.f;
#pragma unroll
        for (int q = 0; q < 4; q++) {
          const f32x4 bq = *(const f32x4*)(bct + q * 4);
          const f32x4 cq = *(const f32x4*)(bct + 16 + q * 4);
#pragma unroll
          for (int j = 0; j < 4; j++) {
            const int s = q * 4 + j;
            pp *= a1;
            h[s] = pp * h[s] + w * bq[j];
            if (j & 1) y1 += h[s] * cq[j]; else y0 += h[s] * cq[j];
          }
        }
        const float yt = (y0 + y1 + uvf[i] * dsk) * silu_f(zvf[i]);
        yp[(size_t)(t8 + i) * DI] = f2bf(yt);
      }
    }
  } else {
    float As[16];
#pragma unroll
    for (int q = 0; q < 4; q++) {
      const f32x4 av = *(const f32x4*)(A_log + (size_t)d * 16 + q * 4);
#pragma unroll
      for (int j = 0; j < 4; j++) As[q * 4 + j] = -__expf(av[j]);
    }
    for (int t8 = 0; t8 < TC; t8 += 8) {
      float dv[8], uvf[8], zvf[8];
#pragma unroll
      for (int i = 0; i < 8; i++) dv[i] = bf2f(dp[(size_t)(t8 + i) * DI]);
#pragma unroll
      for (int i = 0; i < 8; i++) uvf[i] = bf2f(up[(size_t)(t8 + i) * DI]);
#pragma unroll
      for (int i = 0; i < 8; i++) zvf[i] = bf2f(zp[(size_t)(t8 + i) * DI]);
#pragma unroll
      for (int i = 0; i < 8; i++) {
        const float dvi = dv[i];
        const float w = dvi * uvf[i];
        const float* bct = bc + (size_t)(t8 + i) * 32;
        float y0 = 0.f, y1 = 0.f;
#pragma unroll
        for (int q = 0; q < 4; q++) {
          const f32x4 bq = *(const f32x4*)(bct + q * 4);
          const f32x4 cq = *(const f32x4*)(bct + 16 + q * 4);
#pragma unroll
          for (int j = 0; j < 4; j++) {
            const int s = q * 4 + j;
            h[s] = __expf(dvi * As[s]) * h[s] + w * bq[j];
            if (j & 1) y1 += h[s] * cq[j]; else y0 += h[s] * cq[j];
          }
        }
        const float yt = (y0 + y1 + uvf[i] * dsk) * silu_f(zvf[i]);
        yp[(size_t)(t8 + i) * DI] = f2bf(yt);
      }
    }
  }
}

// =================== launch ===================
extern "C" void kernel_launch(void* const* d_in, const int* in_sizes, int n_in,
                              void* d_out, int out_size, void* d_ws, size_t ws_size,
                              hipStream_t stream) {
  const float* x      = (const float*)d_in[0];
  const float* c      = (const float*)d_in[1];
  const float* W_in   = (const float*)d_in[2];
  const float* conv_w = (const float*)d_in[3];
  const float* conv_b = (const float*)d_in[4];
  const float* W_xp   = (const float*)d_in[5];
  const float* W_dt   = (const float*)d_in[6];
  const float* b_dt   = (const float*)d_in[7];
  const float* A_log  = (const float*)d_in[8];
  const float* D_skip = (const float*)d_in[9];
  const float* W_out  = (const float*)d_in[10];
  const float* W_ada  = (const float*)d_in[11];
  const float* b_ada  = (const float*)d_in[12];
  float* out = (float*)d_out;

  char* ws = (char*)d_ws;
  size_t off = 0;
  auto take = [&](size_t bytes) {
    char* p = ws + off;
    off += (bytes + 255) & ~(size_t)255;
    return p;
  };
  float* mod             = (float*)take((size_t)4 * 3072 * 4);
  unsigned short* Wt_in  = (unsigned short*)take((size_t)4096 * 1024 * 2);
  unsigned short* Wt_out = (unsigned short*)take((size_t)1024 * 2048 * 2);
  unsigned short* Wt_xp  = (unsigned short*)take((size_t)128 * 2048 * 2);
  unsigned short* Wt_dt  = (unsigned short*)take((size_t)2048 * 64 * 2);
  unsigned short* h_bf   = (unsigned short*)take((size_t)8192 * 1024 * 2);      // 16MB; then part_T, then hin
  unsigned short* xm     = (unsigned short*)take((size_t)4 * 2048 * 2048 * 2);  // 32MB [m][d]; then y_bf
  unsigned short* z_bf   = (unsigned short*)take((size_t)4 * 2048 * 2048 * 2);  // 32MB [m][d]
  unsigned short* scanws = (unsigned short*)take((size_t)4 * 2048 * 2048 * 2);  // 32MB; hloc(16MB)+dsum(1MB)
  unsigned short* u_bf   = (unsigned short*)take((size_t)8192 * 2048 * 2);      // 32MB [m][d]; u==xc
  unsigned short* delta  = (unsigned short*)take((size_t)8192 * 2048 * 2);      // 32MB [m][d] bf16
  unsigned short* dt_bf  = (unsigned short*)take((size_t)8192 * 64 * 2);
  float* BC              = (float*)take((size_t)4 * 2048 * 32 * 4);             // [m][32]: B|C packed
  int* flag              = (int*)take(256);
  float* part_T = (float*)h_bf;                                   // dead after k_xsplit
  float* hin    = (float*)h_bf;                                   // 16MB exact; written by scanB
  float* hloc   = (float*)scanws;                                 // 16MB
  float* dsum   = (float*)(scanws + (size_t)8 * 1024 * 1024);     // +16MB, 1MB
  unsigned short* y_bf = xm;                                      // xm dead after conv

  // 0. A-structure check + seed mod with bias (blocks 1..48)
  k_chk<<<49, 256, 0, stream>>>(A_log, flag, b_ada, mod);
  // 1. fused pre-pass: ada K-split GEMM (384 blocks, first) + weight transposes (6528)
  k_pre<<<6912, 256, 0, stream>>>(W_in, Wt_in, W_out, Wt_out, W_xp, Wt_xp, W_dt, Wt_dt,
                                  c, W_ada, mod);
  // 2. LN + modulation
  k_ln<<<8192, 256, 0, stream>>>(x, mod, h_bf);
  // 3. in-proj -> xm[m][d], z[m][d]
  GArgs a1{h_bf, Wt_in, 1024, 1024, 1024, nullptr, xm, z_bf, nullptr, nullptr};
  k_gemm<0><<<dim3(64, 32), 256, 0, stream>>>(a1);
  // 4. conv + silu -> u[m][d]
  k_conv<<<dim3(64, 32, 4), 256, 0, stream>>>(xm, conv_w, conv_b, u_bf);
  // 5. x-proj (split-K)
  GArgs a2{u_bf, Wt_xp, 2048, 2048, 512, part_T, nullptr, nullptr, nullptr, nullptr};
  k_gemm<1><<<dim3(64, 1, 4), 256, 0, stream>>>(a2);
  // 6. reduce + split (dt rows; BC[m][32])
  k_xsplit<<<3072, 256, 0, stream>>>(part_T, dt_bf, BC);
  // 7. dt-proj + softplus -> delta[m][d] bf16
  GArgs a3{dt_bf, Wt_dt, 64, 64, 64, nullptr, delta, nullptr, b_dt, nullptr};
  k_gemm<2><<<dim3(64, 16), 256, 0, stream>>>(a3);
  // 8. chunked selective scan, [m][d] coalesced, incremental exp-chain fast path
  k_scanA<<<dim3(8, 4, NC - 1), 256, 0, stream>>>(delta, u_bf, BC, A_log, flag, hloc, dsum);
  k_scanB<<<32, 256, 0, stream>>>(hloc, dsum, A_log, flag, hin);
  k_scanC<<<dim3(8, 4, NC), 256, 0, stream>>>(delta, u_bf, z_bf, BC, A_log, D_skip, flag, hin, y_bf);
  // 9. out-proj + residual + gate
  GArgs a4{y_bf, Wt_out, 2048, 2048, 2048, out, nullptr, nullptr, x, mod};
  k_gemm<3><<<dim3(64, 8), 256, 0, stream>>>(a4);
}